// Round 9
// baseline (602.865 us; speedup 1.0000x reference)
//
#include <hip/hip_runtime.h>
#include <hip/hip_bf16.h>
#include <stdint.h>

typedef __bf16 bf16_t;
typedef float f32x4 __attribute__((ext_vector_type(4)));
typedef __bf16 bf16x8 __attribute__((ext_vector_type(8)));

#define NNODES 10000
#define NEDGES 320000
#define NPAD   10048   // 157*64
#define NPB    8       // dst nodes per edge-kernel block
#define NBLK   (NPAD / NPB)   // 1256

// ---- ws layout (bytes, offsets 256-aligned) ----
#define OFF_AGG   256
#define OFF_JIN   (OFF_AGG  + (size_t)NPAD * 256 * 4)
#define OFF_HIST  (OFF_JIN  + (size_t)2 * NEDGES * 4)
#define OFF_CUR   (OFF_HIST + 10240 * 4)
#define OFF_CSR   (OFF_CUR  + 10240 * 4)
#define OFF_PERM  (OFF_CSR  + 10240 * 4)
#define OFF_SRCS  (OFF_PERM + (size_t)NEDGES * 4)
#define OFF_DSTS  (OFF_SRCS + (size_t)NEDGES * 4)
#define OFF_CES   (OFF_DSTS + (size_t)NEDGES * 4)
#define OFF_CE    (OFF_CES  + (size_t)NEDGES * 4)
#define OFF_WB    (OFF_CE   + (size_t)NEDGES * 4)
// wb element offsets
#define FW1B 0
#define FW2B 16384
#define W1B  81920
#define W2B  147456
#define W3B  212992
#define FB1B 278528
#define FB2B 278784
#define B2B  279040
#define B3B  279296
#define WBN  279552
#define WS_NEED (OFF_WB + (size_t)WBN * 2)
#define OFF_BASC  ((WS_NEED + 255) & ~(size_t)255)
#define WS_NEED_BIG (OFF_BASC + (size_t)NEDGES * 64 * 2)

__device__ __forceinline__ float ssp_f(float v) {
    return fmaxf(v, 0.f) + __logf(1.f + __expf(-fabsf(v))) - 0.69314718055994531f;
}
__device__ __forceinline__ f32x4 mfma16(bf16x8 a, bf16x8 b, f32x4 c) {
    return __builtin_amdgcn_mfma_f32_16x16x32_bf16(a, b, c, 0, 0, 0);
}
template<bool ISB>
__device__ __forceinline__ bf16x8 ld8(const void* p, size_t off) {
    if constexpr (ISB) return *(const bf16x8*)((const bf16_t*)p + off);
    else {
        const float* f = (const float*)p + off;
        f32x4 lo = *(const f32x4*)f, hi = *(const f32x4*)(f + 4);
        bf16x8 r;
        #pragma unroll
        for (int j = 0; j < 4; ++j) { r[j] = (bf16_t)lo[j]; r[j + 4] = (bf16_t)hi[j]; }
        return r;
    }
}
__device__ __forceinline__ bf16x8 ld8r(bool isb, const void* p, size_t off) {
    if (isb) return *(const bf16x8*)((const bf16_t*)p + off);
    const float* f = (const float*)p + off;
    f32x4 lo = *(const f32x4*)f, hi = *(const f32x4*)(f + 4);
    bf16x8 r;
    #pragma unroll
    for (int j = 0; j < 4; ++j) { r[j] = (bf16_t)lo[j]; r[j + 4] = (bf16_t)hi[j]; }
    return r;
}
__device__ __forceinline__ void st1r(bool isb, void* p, size_t off, float v) {
    if (isb) ((bf16_t*)p)[off] = (bf16_t)v;
    else     ((float*)p)[off] = v;
}
__device__ __forceinline__ float ld1r(bool isb, const void* p, size_t off) {
    return isb ? (float)((const bf16_t*)p)[off] : ((const float*)p)[off];
}
// async global->LDS, 16 B per lane; lds dest must be wave-uniform base (+ lane*16)
__device__ __forceinline__ void gld_lds16(const bf16_t* g, bf16_t* l) {
    __builtin_amdgcn_global_load_lds(
        (const __attribute__((address_space(1))) unsigned int*)g,
        (__attribute__((address_space(3))) unsigned int*)l,
        16, 0, 0);
}

// flags[0]=1 if float inputs bf16; flags[1]=1 if ji_pairs int64. Also zero hist.
__global__ __launch_bounds__(256) void detect_kernel(
    const void* __restrict__ x, const int* __restrict__ jraw,
    int* __restrict__ flags, int* __restrict__ hist)
{
    __shared__ int cnt, hi;
    if (threadIdx.x == 0) { cnt = 0; hi = 0; }
    __syncthreads();
    const unsigned short* xw = (const unsigned short*)x;
    int local = 0;
    for (int i = threadIdx.x; i < 2048; i += 256) {
        unsigned int e = (xw[2 * i] >> 7) & 0xFF;
        if (e >= 100 && e <= 141) local++;
    }
    atomicAdd(&cnt, local);
    int v = 0;
    for (int i = threadIdx.x; i < 1024; i += 256) v |= jraw[2 * i + 1];
    if (v != 0) atomicOr(&hi, 1);
    for (int i = threadIdx.x; i < 10240; i += 256) hist[i] = 0;
    __syncthreads();
    if (threadIdx.x == 0) { flags[0] = (cnt > 1024) ? 1 : 0; flags[1] = (hi == 0) ? 1 : 0; }
}

// jin normalize+clamp + hist; ce precompute; weights -> bf16; optional basis->bf16
__global__ __launch_bounds__(256) void prep_kernel(
    const int* __restrict__ raw, const int* __restrict__ flags,
    const void* __restrict__ e_ji, const void* __restrict__ basis,
    const void* fw1, const void* fb1, const void* fw2, const void* fb2,
    const void* w1, const void* w2, const void* b2, const void* w3, const void* b3,
    int* __restrict__ jin, int* __restrict__ hist, float* __restrict__ ce,
    bf16_t* __restrict__ wb, bf16_t* __restrict__ basc, int doconv)
{
    const bool is64 = (flags[1] != 0);
    const bool isb  = (flags[0] != 0);
    const int gid = blockIdx.x * 256 + threadIdx.x;
    if (gid < 2 * NEDGES) {
        int iv = is64 ? raw[2 * gid] : raw[gid];
        iv = iv < 0 ? 0 : (iv >= NNODES ? NNODES - 1 : iv);
        jin[gid] = iv;
        if (gid >= NEDGES) atomicAdd(&hist[iv], 1);
    }
    if (gid < NEDGES)
        ce[gid] = 0.25f * (cosf(3.14159265358979f * ld1r(isb, e_ji, gid)) + 1.0f);
    if (gid < WBN) {
        int g = gid; const void* s; int so;
        if      (g < FW2B) { s = fw1; so = g - FW1B; }
        else if (g < W1B)  { s = fw2; so = g - FW2B; }
        else if (g < W2B)  { s = w1;  so = g - W1B; }
        else if (g < W3B)  { s = w2;  so = g - W2B; }
        else if (g < FB1B) { s = w3;  so = g - W3B; }
        else if (g < FB2B) { s = fb1; so = g - FB1B; }
        else if (g < B2B)  { s = fb2; so = g - FB2B; }
        else if (g < B3B)  { s = b2;  so = g - B2B; }
        else               { s = b3;  so = g - B3B; }
        wb[gid] = (bf16_t)ld1r(isb, s, so);
    }
    if (doconv) {
        const int nv = NEDGES * 64 / 8;
        for (int i = gid; i < nv; i += gridDim.x * 256)
            ((bf16x8*)basc)[i] = ld8r(isb, basis, (size_t)i * 8);
    }
}

// exclusive scan of hist -> cur (scatter cursor) AND csr (row starts)
__global__ __launch_bounds__(256) void scan_kernel(
    const int* __restrict__ hist, int* __restrict__ cur, int* __restrict__ csr)
{
    __shared__ int s[256];
    const int t = threadIdx.x;
    int loc[40]; int sum = 0;
    const int base = t * 40;
    #pragma unroll
    for (int j = 0; j < 40; ++j) {
        int i = base + j;
        loc[j] = (i < NNODES) ? hist[i] : 0;
        sum += loc[j];
    }
    s[t] = sum; __syncthreads();
    for (int off = 1; off < 256; off <<= 1) {
        int v = (t >= off) ? s[t - off] : 0;
        __syncthreads();
        if (t >= off) s[t] += v;
        __syncthreads();
    }
    int pre = (t == 0) ? 0 : s[t - 1];
    #pragma unroll
    for (int j = 0; j < 40; ++j) {
        int i = base + j;
        cur[i] = pre;
        csr[i] = pre;
        pre += loc[j];
    }
}

__global__ __launch_bounds__(256) void scatter_kernel(
    const int* __restrict__ jin, const float* __restrict__ ce,
    int* __restrict__ cur, int* __restrict__ perm,
    int* __restrict__ src_s, int* __restrict__ dst_s, float* __restrict__ ce_s)
{
    int e = blockIdx.x * 256 + threadIdx.x;
    if (e < NEDGES) {
        int d = jin[NEDGES + e];
        int pos = atomicAdd(&cur[d], 1);
        perm[pos]  = e;
        src_s[pos] = jin[e];
        dst_s[pos] = d;
        ce_s[pos]  = ce[e];
    }
}

// h = x @ w1.T (runtime input dtype), h bf16 in d_out front region
__global__ __launch_bounds__(256, 2) void h_gemm_kernel(
    const void* __restrict__ x, const bf16_t* __restrict__ wb,
    bf16_t* __restrict__ h, const int* __restrict__ flags)
{
    const bool isb = (flags[0] != 0);
    const bf16_t* w1b = wb + W1B;
    const int w = threadIdx.x >> 6, L = threadIdx.x & 63;
    const int lane16 = L & 15, quad = L >> 4;
    const int nb = blockIdx.x * 64, cb = w * 64;
    f32x4 acc[4][4] = {};
    #pragma unroll
    for (int kc = 0; kc < 8; ++kc) {
        const int ko = kc * 32 + quad * 8;
        bf16x8 af[4], bfr[4];
        #pragma unroll
        for (int mt = 0; mt < 4; ++mt) {
            int row = nb + mt * 16 + lane16;
            if (row >= NNODES) row = NNODES - 1;
            af[mt] = ld8r(isb, x, (size_t)row * 256 + ko);
        }
        #pragma unroll
        for (int nt = 0; nt < 4; ++nt)
            bfr[nt] = *(const bf16x8*)(w1b + (size_t)(cb + nt * 16 + lane16) * 256 + ko);
        #pragma unroll
        for (int mt = 0; mt < 4; ++mt)
            #pragma unroll
            for (int nt = 0; nt < 4; ++nt)
                acc[mt][nt] = mfma16(af[mt], bfr[nt], acc[mt][nt]);
    }
    #pragma unroll
    for (int mt = 0; mt < 4; ++mt)
        #pragma unroll
        for (int r = 0; r < 4; ++r) {
            int row = nb + mt * 16 + quad * 4 + r;
            if (row < NNODES)
                #pragma unroll
                for (int nt = 0; nt < 4; ++nt)
                    h[(size_t)row * 256 + cb + nt * 16 + lane16] = (bf16_t)acc[mt][nt][r];
        }
}

// Software-pipelined fused edge kernel: no global atomics, meta+basis prefetched
// one subtile ahead, h staged via global_load_lds. guard<0: always run;
// else run iff (flags[0]!=0)==(guard==1).
template<bool ISB>
__global__ __launch_bounds__(256, 2) void edge_pipe_kernel(
    const void* __restrict__ basis, const int* __restrict__ csr,
    const int* __restrict__ perm, const int* __restrict__ src_s,
    const int* __restrict__ dst_s, const float* __restrict__ ce_s,
    const bf16_t* __restrict__ wb, const bf16_t* __restrict__ h,
    float* __restrict__ agg, const int* __restrict__ flags, int guard)
{
    if (guard >= 0 && ((flags[0] != 0) != (guard == 1))) return;
    __shared__ bf16_t T[64][264];      // filter matrix (padded: GEMM2 A reads)
    __shared__ bf16_t Hs[64 * 256];    // gathered h rows (unpadded: global_load_lds)
    __shared__ float G[NPB][260];      // per-block agg tile
    __shared__ int   smeta[2][3][64];  // [buf][perm|src|nrow][edge]
    __shared__ float smce[2][64];

    const int tid = threadIdx.x;
    const int w = tid >> 6, L = tid & 63;
    const int lane16 = L & 15, quad = L >> 4;
    const int cb = w * 64;
    const int nbase  = blockIdx.x * NPB;
    const int estart = csr[nbase];
    const int eend   = csr[nbase + NPB];

    for (int i = tid; i < NPB * 260; i += 256) (&G[0][0])[i] = 0.f;

    const bf16_t* fw1b = wb + FW1B;
    const bf16_t* fw2b = wb + FW2B;
    float fb1v[4], fb2v[4];
    #pragma unroll
    for (int nt = 0; nt < 4; ++nt) {
        fb1v[nt] = (float)wb[FB1B + cb + nt * 16 + lane16];
        fb2v[nt] = (float)wb[FB2B + cb + nt * 16 + lane16];
    }

    const int e0beg = estart & ~63;
    const int nsub  = (eend - e0beg + 63) >> 6;
    const int esafe = (estart < NEDGES) ? estart : NEDGES - 1;

    // ---- prologue: meta[0] ----
    {
        int e = e0beg + L;
        bool valid = (e >= estart) && (e < eend);
        int ee = valid ? e : esafe;
        if      (w == 0) smeta[0][0][L] = perm[ee];
        else if (w == 1) smeta[0][1][L] = src_s[ee];
        else if (w == 2) {
            int nr = dst_s[ee] - nbase;
            smeta[0][2][L] = nr < 0 ? 0 : (nr > NPB - 1 ? NPB - 1 : nr);
        }
        else smce[0][L] = valid ? ce_s[ee] : 0.f;
    }
    __syncthreads();

    // basis[0] fragments
    bf16x8 bcur[8];
    #pragma unroll
    for (int mt = 0; mt < 4; ++mt) {
        int prow = smeta[0][0][mt * 16 + lane16];
        #pragma unroll
        for (int kc = 0; kc < 2; ++kc)
            bcur[kc * 4 + mt] = ld8<ISB>(basis, (size_t)prow * 64 + kc * 32 + quad * 8);
    }

    for (int si = 0; si < nsub; ++si) {
        const int buf = si & 1;
        // (a) meta[si+1] -> regs
        int miv = 0; float mfv = 0.f;
        {
            int sn = (si + 1 < nsub) ? si + 1 : si;
            int e = e0beg + sn * 64 + L;
            bool valid = (e >= estart) && (e < eend);
            int ee = valid ? e : esafe;
            if      (w == 0) miv = perm[ee];
            else if (w == 1) miv = src_s[ee];
            else if (w == 2) {
                int nr = dst_s[ee] - nbase;
                miv = nr < 0 ? 0 : (nr > NPB - 1 ? NPB - 1 : nr);
            }
            else mfv = valid ? ce_s[ee] : 0.f;
        }

        // (b) GEMM1 from bcur
        f32x4 acc1[4][4] = {};
        #pragma unroll
        for (int kc = 0; kc < 2; ++kc) {
            bf16x8 bfr[4];
            #pragma unroll
            for (int nt = 0; nt < 4; ++nt)
                bfr[nt] = *(const bf16x8*)(fw1b + (size_t)(cb + nt * 16 + lane16) * 64 + kc * 32 + quad * 8);
            #pragma unroll
            for (int mt = 0; mt < 4; ++mt)
                #pragma unroll
                for (int nt = 0; nt < 4; ++nt)
                    acc1[mt][nt] = mfma16(bcur[kc * 4 + mt], bfr[nt], acc1[mt][nt]);
        }
        // (c) ssp -> T
        #pragma unroll
        for (int nt = 0; nt < 4; ++nt) {
            int col = cb + nt * 16 + lane16;
            #pragma unroll
            for (int mt = 0; mt < 4; ++mt)
                #pragma unroll
                for (int r = 0; r < 4; ++r)
                    T[mt * 16 + quad * 4 + r][col] = (bf16_t)ssp_f(acc1[mt][nt][r] + fb1v[nt]);
        }
        // (d) commit meta[si+1]
        if (w == 3) smce[buf ^ 1][L] = mfv;
        else        smeta[buf ^ 1][w][L] = miv;
        __syncthreads();   // S1: T(filter) + meta[si+1] ready

        // (f) h[si] -> Hs via global_load_lds (drained at S2)
        #pragma unroll
        for (int j = 0; j < 8; ++j) {
            int row = w * 16 + j * 2 + (L >> 5);
            int srcrow = smeta[buf][1][row];
            gld_lds16(h + (size_t)srcrow * 256 + (L & 31) * 8,
                      &Hs[w * 4096 + j * 512]);
        }
        // (g) basis[si+1] prefetch -> regs
        bf16x8 bnext[8];
        #pragma unroll
        for (int mt = 0; mt < 4; ++mt) {
            int prow = smeta[buf ^ 1][0][mt * 16 + lane16];
            #pragma unroll
            for (int kc = 0; kc < 2; ++kc)
                bnext[kc * 4 + mt] = ld8<ISB>(basis, (size_t)prow * 64 + kc * 32 + quad * 8);
        }

        // (h) GEMM2: T @ fw2b
        f32x4 acc2[4][4] = {};
        #pragma unroll
        for (int kc = 0; kc < 8; ++kc) {
            const int ko = kc * 32 + quad * 8;
            bf16x8 af[4], bfr[4];
            #pragma unroll
            for (int mt = 0; mt < 4; ++mt)
                af[mt] = *(const bf16x8*)(&T[mt * 16 + lane16][ko]);
            #pragma unroll
            for (int nt = 0; nt < 4; ++nt)
                bfr[nt] = *(const bf16x8*)(fw2b + (size_t)(cb + nt * 16 + lane16) * 256 + ko);
            #pragma unroll
            for (int mt = 0; mt < 4; ++mt)
                #pragma unroll
                for (int nt = 0; nt < 4; ++nt)
                    acc2[mt][nt] = mfma16(af[mt], bfr[nt], acc2[mt][nt]);
        }
        __syncthreads();   // S2: T free, Hs landed

        // (j) epilogue: run-merged accumulate into G (fully unrolled)
        float run[4] = {0.f, 0.f, 0.f, 0.f};
        int curn = -1;
        #pragma unroll
        for (int mt = 0; mt < 4; ++mt)
            #pragma unroll
            for (int r = 0; r < 4; ++r) {
                int row = mt * 16 + quad * 4 + r;
                int nr = smeta[buf][2][row];
                if (nr != curn) {
                    if (curn >= 0) {
                        #pragma unroll
                        for (int nt = 0; nt < 4; ++nt)
                            atomicAdd(&G[curn][cb + nt * 16 + lane16], run[nt]);
                    }
                    curn = nr;
                    #pragma unroll
                    for (int nt = 0; nt < 4; ++nt) run[nt] = 0.f;
                }
                float cv = smce[buf][row];
                #pragma unroll
                for (int nt = 0; nt < 4; ++nt) {
                    int col = cb + nt * 16 + lane16;
                    run[nt] += (acc2[mt][nt][r] + fb2v[nt]) * cv * (float)Hs[row * 256 + col];
                }
            }
        #pragma unroll
        for (int nt = 0; nt < 4; ++nt)
            atomicAdd(&G[curn][cb + nt * 16 + lane16], run[nt]);
        __syncthreads();   // S3: Hs/T/meta free

        #pragma unroll
        for (int k = 0; k < 8; ++k) bcur[k] = bnext[k];
    }
    __syncthreads();

    // plain coalesced store of the block's agg rows
    #pragma unroll
    for (int n = 0; n < NPB; ++n)
        agg[(size_t)(nbase + n) * 256 + tid] = G[n][tid];
}

// out = ssp(agg @ w2.T + b2) @ w3.T + b3 (runtime output dtype)
__global__ __launch_bounds__(256, 2) void out_kernel(
    const float* __restrict__ agg, const bf16_t* __restrict__ wb,
    void* __restrict__ out, const int* __restrict__ flags)
{
    const bool isb = (flags[0] != 0);
    const bf16_t* w2b = wb + W2B;
    const bf16_t* w3b = wb + W3B;
    __shared__ bf16_t U[64][264];
    const int w = threadIdx.x >> 6, L = threadIdx.x & 63;
    const int lane16 = L & 15, quad = L >> 4;
    const int nb = blockIdx.x * 64, cb = w * 64;

    f32x4 acc[4][4] = {};
    #pragma unroll
    for (int kc = 0; kc < 8; ++kc) {
        const int ko = kc * 32 + quad * 8;
        bf16x8 af[4], bfr[4];
        #pragma unroll
        for (int mt = 0; mt < 4; ++mt) {
            int row = nb + mt * 16 + lane16;
            const float* p = agg + (size_t)row * 256 + ko;
            f32x4 lo = *(const f32x4*)p, hi = *(const f32x4*)(p + 4);
            bf16x8 a;
            #pragma unroll
            for (int j = 0; j < 4; ++j) { a[j] = (bf16_t)lo[j]; a[j + 4] = (bf16_t)hi[j]; }
            af[mt] = a;
        }
        #pragma unroll
        for (int nt = 0; nt < 4; ++nt)
            bfr[nt] = *(const bf16x8*)(w2b + (size_t)(cb + nt * 16 + lane16) * 256 + ko);
        #pragma unroll
        for (int mt = 0; mt < 4; ++mt)
            #pragma unroll
            for (int nt = 0; nt < 4; ++nt)
                acc[mt][nt] = mfma16(af[mt], bfr[nt], acc[mt][nt]);
    }
    #pragma unroll
    for (int nt = 0; nt < 4; ++nt) {
        int col = cb + nt * 16 + lane16;
        float bias = (float)wb[B2B + col];
        #pragma unroll
        for (int mt = 0; mt < 4; ++mt)
            #pragma unroll
            for (int r = 0; r < 4; ++r)
                U[mt * 16 + quad * 4 + r][col] = (bf16_t)ssp_f(acc[mt][nt][r] + bias);
    }
    __syncthreads();

    f32x4 acc2[4][4] = {};
    #pragma unroll
    for (int kc = 0; kc < 8; ++kc) {
        const int ko = kc * 32 + quad * 8;
        bf16x8 af[4], bfr[4];
        #pragma unroll
        for (int mt = 0; mt < 4; ++mt)
            af[mt] = *(const bf16x8*)(&U[mt * 16 + lane16][ko]);
        #pragma unroll
        for (int nt = 0; nt < 4; ++nt)
            bfr[nt] = *(const bf16x8*)(w3b + (size_t)(cb + nt * 16 + lane16) * 256 + ko);
        #pragma unroll
        for (int mt = 0; mt < 4; ++mt)
            #pragma unroll
            for (int nt = 0; nt < 4; ++nt)
                acc2[mt][nt] = mfma16(af[mt], bfr[nt], acc2[mt][nt]);
    }
    #pragma unroll
    for (int mt = 0; mt < 4; ++mt)
        #pragma unroll
        for (int r = 0; r < 4; ++r) {
            int row = nb + mt * 16 + quad * 4 + r;
            if (row < NNODES)
                #pragma unroll
                for (int nt = 0; nt < 4; ++nt) {
                    int col = cb + nt * 16 + lane16;
                    st1r(isb, out, (size_t)row * 256 + col,
                         acc2[mt][nt][r] + (float)wb[B3B + col]);
                }
        }
}

extern "C" void kernel_launch(void* const* d_in, const int* in_sizes, int n_in,
                              void* d_out, int out_size, void* d_ws, size_t ws_size,
                              hipStream_t stream) {
    const void* x     = d_in[0];
    const int*  ji    = (const int*)d_in[1];
    const void* e_ji  = d_in[2];
    const void* basis = d_in[3];
    const void* fw1   = d_in[4];
    const void* fb1   = d_in[5];
    const void* fw2   = d_in[6];
    const void* fb2   = d_in[7];
    const void* w1    = d_in[8];
    const void* w2    = d_in[9];
    const void* b2    = d_in[10];
    const void* w3    = d_in[11];
    const void* b3    = d_in[12];

    if (ws_size < WS_NEED) return;
    const bool bigws = ws_size >= WS_NEED_BIG;

    char* W = (char*)d_ws;
    int*    flags = (int*)W;
    float*  agg   = (float*)(W + OFF_AGG);
    int*    jin   = (int*)(W + OFF_JIN);
    int*    hist  = (int*)(W + OFF_HIST);
    int*    cur   = (int*)(W + OFF_CUR);
    int*    csr   = (int*)(W + OFF_CSR);
    int*    perm  = (int*)(W + OFF_PERM);
    int*    src_s = (int*)(W + OFF_SRCS);
    int*    dst_s = (int*)(W + OFF_DSTS);
    float*  ce_s  = (float*)(W + OFF_CES);
    float*  ce    = (float*)(W + OFF_CE);
    bf16_t* wb    = (bf16_t*)(W + OFF_WB);
    bf16_t* basc  = (bf16_t*)(W + OFF_BASC);
    bf16_t* h     = (bf16_t*)d_out;   // scratch; overwritten by out_kernel

    detect_kernel<<<1, 256, 0, stream>>>(x, ji, flags, hist);
    prep_kernel<<<2500, 256, 0, stream>>>(ji, flags, e_ji, basis, fw1, fb1, fw2, fb2,
                                          w1, w2, b2, w3, b3, jin, hist, ce, wb,
                                          basc, bigws ? 1 : 0);
    scan_kernel<<<1, 256, 0, stream>>>(hist, cur, csr);
    scatter_kernel<<<1250, 256, 0, stream>>>(jin, ce, cur, perm, src_s, dst_s, ce_s);
    h_gemm_kernel<<<157, 256, 0, stream>>>(x, wb, h, flags);
    if (bigws) {
        edge_pipe_kernel<true><<<NBLK, 256, 0, stream>>>(basc, csr, perm, src_s, dst_s,
                                                         ce_s, wb, h, agg, flags, -1);
    } else {
        edge_pipe_kernel<true ><<<NBLK, 256, 0, stream>>>(basis, csr, perm, src_s, dst_s,
                                                          ce_s, wb, h, agg, flags, 1);
        edge_pipe_kernel<false><<<NBLK, 256, 0, stream>>>(basis, csr, perm, src_s, dst_s,
                                                          ce_s, wb, h, agg, flags, 0);
    }
    out_kernel<<<157, 256, 0, stream>>>(agg, wb, d_out, flags);
}